// Round 1
// baseline (396.072 us; speedup 1.0000x reference)
//
#include <hip/hip_runtime.h>
#include <math.h>

// Problem constants
#define BATCH 128
#define NPRI  8732
#define CCH   512
#define HH    19      // feature map side
#define NHID  4096
#define FGC   19

// ws layout (float offsets). Total ~21.3 MB.
#define WS_FEAT   0                       // [128*512]
#define WS_H1     65536                   // [128*4096]
#define WS_H2     589824                  // [128*4096]
#define WS_PART   1114112                 // [8*128*4096] = 16MB
#define WS_CAND   5308416                 // cand_score[512]
// then cand_idx[512] (int), cand_car[512] (int), crop int4[128], vflag[128]

// ---------------------------------------------------------------------------
// K1a: per-(batch, quarter-of-N) partial argmax of car score.
// score = p1 if argmax(softmax(conf))==1 else -inf ; first-max tie-break.
// ---------------------------------------------------------------------------
__global__ void k_best_partial(const float* __restrict__ conf,
                               float* __restrict__ cs, int* __restrict__ ci,
                               int* __restrict__ cc) {
  int blk = blockIdx.x;            // 0..511 ; b = blk/4, chunk = blk%4
  int b = blk >> 2, chunk = blk & 3;
  int n0 = chunk * 2183;           // 4*2183 == 8732 exactly
  int t = threadIdx.x;
  const float* cb = conf + (size_t)b * NPRI * 2;
  float bestS = -INFINITY; int bestN = 0x7fffffff; int car_any = 0;
  for (int i = n0 + t; i < n0 + 2183; i += 256) {
    float c0 = cb[2 * i], c1 = cb[2 * i + 1];
    float m = fmaxf(c0, c1);
    float e0 = expf(c0 - m), e1 = expf(c1 - m);
    float s = e0 + e1;
    float p0 = e0 / s, p1 = e1 / s;
    bool car = p1 > p0;            // argmax(probs)==1 needs strict >
    car_any |= (int)car;
    float sc = car ? p1 : -INFINITY;
    if (sc > bestS || (sc == bestS && i < bestN)) { bestS = sc; bestN = i; }
  }
  __shared__ float ls[256]; __shared__ int li[256]; __shared__ int lc[256];
  ls[t] = bestS; li[t] = bestN; lc[t] = car_any;
  __syncthreads();
  for (int off = 128; off > 0; off >>= 1) {
    if (t < off) {
      float s2 = ls[t + off]; int n2 = li[t + off];
      if (s2 > ls[t] || (s2 == ls[t] && n2 < li[t])) { ls[t] = s2; li[t] = n2; }
      lc[t] |= lc[t + off];
    }
    __syncthreads();
  }
  if (t == 0) { cs[blk] = ls[0]; ci[blk] = li[0]; cc[blk] = lc[0]; }
}

// ---------------------------------------------------------------------------
// K1b: combine 4 chunks per batch, decode best box, write boxes/valid outputs
// and integer crop coords for the extract kernel.
// ---------------------------------------------------------------------------
__global__ void k_best_final(const float* __restrict__ loc,
                             const float* __restrict__ priors,
                             const float* __restrict__ cs,
                             const int* __restrict__ ci,
                             const int* __restrict__ cc,
                             float* __restrict__ out_boxes,
                             float* __restrict__ out_valid,
                             int4* __restrict__ crop,
                             int* __restrict__ vflag) {
  int b = threadIdx.x;
  if (b >= BATCH) return;
  float bs = -INFINITY; int bn = 0; int hc = 0;
  #pragma unroll
  for (int p = 0; p < 4; p++) {     // chunks ascend in n: strict > keeps first max
    float s = cs[b * 4 + p]; int n = ci[b * 4 + p];
    hc |= cc[b * 4 + p];
    if (s > bs) { bs = s; bn = n; }
  }
  const float* lp = loc + ((size_t)b * NPRI + bn) * 4;
  const float* pp = priors + (size_t)bn * 4;
  float l0 = lp[0], l1 = lp[1], l2 = lp[2], l3 = lp[3];
  float pcx = pp[0], pcy = pp[1], pw = pp[2], ph = pp[3];
  // decode with the reference's exact op order: priors + (loc*0.1)*priors_wh
  float cx = pcx + (l0 * 0.1f) * pw;
  float cy = pcy + (l1 * 0.1f) * ph;
  float w = pw * expf(l2 * 0.2f);
  float h = ph * expf(l3 * 0.2f);
  float x1 = cx - 0.5f * w;
  float y1 = cy - 0.5f * h;
  float x2 = x1 + w, y2 = y1 + h;   // NOT cx+0.5w: reference does xy1 + wh
  bool geom = (x2 > x1) && (y2 > y1);
  bool valid = hc && geom;
  float r0, r1, r2, r3;
  if (hc) { r0 = x1; r1 = y1; r2 = x2; r3 = y2; }
  else    { r0 = r1 = r2 = r3 = 0.0f; }
  r0 = fminf(fmaxf(r0, 0.0f), 1.0f);
  r1 = fminf(fmaxf(r1, 0.0f), 1.0f);
  r2 = fminf(fmaxf(r2, 0.0f), 1.0f);
  r3 = fminf(fmaxf(r3, 0.0f), 1.0f);
  out_boxes[b * 4 + 0] = r0; out_boxes[b * 4 + 1] = r1;
  out_boxes[b * 4 + 2] = r2; out_boxes[b * 4 + 3] = r3;
  out_valid[b] = valid ? 1.0f : 0.0f;
  // crop coords: floor(clip(clip(r*300,0,300)/step, 0, 18))
  const float stepF = (float)(300.0 / 19.0);
  float q0 = fminf(fmaxf(r0 * 300.0f, 0.0f), 300.0f) / stepF;
  float q1 = fminf(fmaxf(r1 * 300.0f, 0.0f), 300.0f) / stepF;
  float q2 = fminf(fmaxf(r2 * 300.0f, 0.0f), 300.0f) / stepF;
  float q3 = fminf(fmaxf(r3 * 300.0f, 0.0f), 300.0f) / stepF;
  int ix1 = (int)floorf(fminf(fmaxf(q0, 0.0f), 18.0f));
  int iy1 = (int)floorf(fminf(fmaxf(q1, 0.0f), 18.0f));
  int ix2 = (int)floorf(fminf(fmaxf(q2, 0.0f), 18.0f));
  int iy2 = (int)floorf(fminf(fmaxf(q3, 0.0f), 18.0f));
  crop[b] = make_int4(ix1, iy1, ix2, iy2);
  vflag[b] = valid ? 1 : 0;
}

// ---------------------------------------------------------------------------
// K2: crop + global max pool. One wave per (b, c); region rows are contiguous.
// ---------------------------------------------------------------------------
__global__ void k_extract(const float* __restrict__ fin,
                          const int4* __restrict__ crop,
                          const int* __restrict__ vflag,
                          float* __restrict__ feat) {
  int blk = blockIdx.x;            // B * (C/4) = 16384
  int b = blk >> 7;
  int tile = blk & 127;
  int wave = threadIdx.x >> 6;
  int lane = threadIdx.x & 63;
  int c = tile * 4 + wave;
  if (!vflag[b]) {
    if (lane == 0) feat[b * CCH + c] = 0.0f;
    return;
  }
  int4 cr = crop[b];
  int wcnt = cr.z - cr.x + 1;
  int cnt = wcnt * (cr.w - cr.y + 1);
  const float* p = fin + (size_t)(b * CCH + c) * (HH * HH);
  float m = -INFINITY;
  for (int i = lane; i < cnt; i += 64) {
    int yy = cr.y + i / wcnt;
    int xx = cr.x + i % wcnt;
    m = fmaxf(m, p[yy * HH + xx]);
  }
  #pragma unroll
  for (int off = 32; off > 0; off >>= 1) m = fmaxf(m, __shfl_xor(m, off));
  if (lane == 0) feat[b * CCH + c] = m;
}

// ---------------------------------------------------------------------------
// K3: fp32 GEMM, M=128 fixed, N=4096, K-split into KSPL partial buffers.
// Block: 256 thr, output tile 128m x 128n; thread: 32 m x 2 n (acc 64 regs).
// A tile (32k x 128m) staged transposed in LDS; broadcast float4 reads.
// ---------------------------------------------------------------------------
template <int KSPL>
__global__ __launch_bounds__(256) void k_gemm(const float* __restrict__ A,
                                              const float* __restrict__ W,
                                              float* __restrict__ part, int K) {
  const int N = 4096;
  int nb = blockIdx.x;             // 32 n-tiles of 128
  int ks = blockIdx.y;             // K-split index
  int Kper = K / KSPL;
  int k0base = ks * Kper;
  int t = threadIdx.x;
  __shared__ float As[32][128];    // 16 KB, [kk][m]
  int lane = t & 63, wave = t >> 6;
  int n0 = nb * 128 + lane * 2;    // 2 consecutive n per thread (float2)
  int mB = wave * 32;              // 32 m per thread
  float acc0[32], acc1[32];
  #pragma unroll
  for (int i = 0; i < 32; i++) { acc0[i] = 0.0f; acc1[i] = 0.0f; }
  int lm = t >> 1;                 // loader: row m
  int lkb = (t & 1) * 16;          // loader: k sub-block
  for (int k0 = k0base; k0 < k0base + Kper; k0 += 32) {
    float v[16];
    const float* src = A + (size_t)lm * K + k0 + lkb;
    #pragma unroll
    for (int j = 0; j < 16; j += 4) {
      float4 t4 = *(const float4*)(src + j);
      v[j] = t4.x; v[j + 1] = t4.y; v[j + 2] = t4.z; v[j + 3] = t4.w;
    }
    __syncthreads();
    #pragma unroll
    for (int j = 0; j < 16; j++) As[lkb + j][lm] = v[j];
    __syncthreads();
    #pragma unroll 8
    for (int kk = 0; kk < 32; kk++) {
      float2 wv = *(const float2*)(W + (size_t)(k0 + kk) * N + n0);
      const float4* ap = (const float4*)&As[kk][mB];   // wave-uniform: broadcast
      #pragma unroll
      for (int q = 0; q < 8; q++) {
        float4 av = ap[q];
        acc0[q * 4 + 0] += av.x * wv.x; acc1[q * 4 + 0] += av.x * wv.y;
        acc0[q * 4 + 1] += av.y * wv.x; acc1[q * 4 + 1] += av.y * wv.y;
        acc0[q * 4 + 2] += av.z * wv.x; acc1[q * 4 + 2] += av.z * wv.y;
        acc0[q * 4 + 3] += av.w * wv.x; acc1[q * 4 + 3] += av.w * wv.y;
      }
    }
  }
  float* dst = part + (size_t)ks * (BATCH * N);
  #pragma unroll
  for (int i = 0; i < 32; i++) {
    *(float2*)(dst + (size_t)(mB + i) * N + n0) = make_float2(acc0[i], acc1[i]);
  }
}

// ---------------------------------------------------------------------------
// K4: sum KSPL partials + bias (+ReLU). 524288 elements, float4 per thread.
// ---------------------------------------------------------------------------
template <int KSPL, bool RELU>
__global__ void k_finalize(const float* __restrict__ part,
                           const float* __restrict__ bias,
                           float* __restrict__ out) {
  int idx = (blockIdx.x * 256 + threadIdx.x) * 4;   // grid 512 -> 524288
  float4 s = *(const float4*)(part + idx);
  #pragma unroll
  for (int p = 1; p < KSPL; p++) {
    float4 v = *(const float4*)(part + (size_t)p * (BATCH * NHID) + idx);
    s.x += v.x; s.y += v.y; s.z += v.z; s.w += v.w;
  }
  float4 bv = *(const float4*)(bias + (idx & (NHID - 1)));
  s.x += bv.x; s.y += bv.y; s.z += bv.z; s.w += bv.w;
  if (RELU) {
    s.x = fmaxf(s.x, 0.0f); s.y = fmaxf(s.y, 0.0f);
    s.z = fmaxf(s.z, 0.0f); s.w = fmaxf(s.w, 0.0f);
  }
  *(float4*)(out + idx) = s;
}

// ---------------------------------------------------------------------------
// K5: final projection [128,4096] @ [4096,19] + b3. Block per row m.
// w3 k-tiles staged in LDS; cross-thread tree reduce.
// ---------------------------------------------------------------------------
__global__ void k_gemm3(const float* __restrict__ h2,
                        const float* __restrict__ w3,
                        const float* __restrict__ b3,
                        float* __restrict__ out) {
  int m = blockIdx.x;
  int t = threadIdx.x;
  __shared__ float wl[512 * 19];    // 38.9 KB
  __shared__ float red[256][19];    // 19.4 KB (stride 19: conflict-free)
  float acc[19];
  #pragma unroll
  for (int j = 0; j < 19; j++) acc[j] = 0.0f;
  const float* hrow = h2 + (size_t)m * NHID;
  for (int k0 = 0; k0 < NHID; k0 += 512) {
    __syncthreads();
    for (int i = t; i < 512 * 19; i += 256) wl[i] = w3[k0 * 19 + i];
    __syncthreads();
    for (int kk = t; kk < 512; kk += 256) {
      float hv = hrow[k0 + kk];
      #pragma unroll
      for (int j = 0; j < 19; j++) acc[j] += hv * wl[kk * 19 + j];
    }
  }
  __syncthreads();
  #pragma unroll
  for (int j = 0; j < 19; j++) red[t][j] = acc[j];
  __syncthreads();
  for (int off = 128; off > 0; off >>= 1) {
    if (t < off) {
      #pragma unroll
      for (int j = 0; j < 19; j++) red[t][j] += red[t + off][j];
    }
    __syncthreads();
  }
  if (t < FGC) out[m * FGC + t] = red[0][t] + b3[t];
}

// ---------------------------------------------------------------------------
extern "C" void kernel_launch(void* const* d_in, const int* in_sizes, int n_in,
                              void* d_out, int out_size, void* d_ws, size_t ws_size,
                              hipStream_t stream) {
  const float* loc      = (const float*)d_in[0];
  const float* conf     = (const float*)d_in[1];
  const float* priors   = (const float*)d_in[2];
  const float* features = (const float*)d_in[3];
  const float* w1 = (const float*)d_in[4];
  const float* b1 = (const float*)d_in[5];
  const float* w2 = (const float*)d_in[6];
  const float* b2 = (const float*)d_in[7];
  const float* w3 = (const float*)d_in[8];
  const float* b3 = (const float*)d_in[9];
  float* out = (float*)d_out;      // [128*19 fg_cls][128*4 boxes][128 valid]
  float* ws = (float*)d_ws;

  float* feat = ws + WS_FEAT;
  float* h1   = ws + WS_H1;
  float* h2   = ws + WS_H2;
  float* part = ws + WS_PART;
  float* cs   = ws + WS_CAND;
  int*   ci   = (int*)(ws + WS_CAND + 512);
  int*   cc   = ci + 512;
  int4*  crop = (int4*)(cc + 512);
  int*   vfl  = (int*)(crop + BATCH);

  k_best_partial<<<512, 256, 0, stream>>>(conf, cs, ci, cc);
  k_best_final<<<1, 128, 0, stream>>>(loc, priors, cs, ci, cc,
                                      out + BATCH * FGC,
                                      out + BATCH * FGC + BATCH * 4, crop, vfl);
  k_extract<<<BATCH * (CCH / 4), 256, 0, stream>>>(features, crop, vfl, feat);
  k_gemm<4><<<dim3(32, 4), 256, 0, stream>>>(feat, w1, part, 512);
  k_finalize<4, true><<<512, 256, 0, stream>>>(part, b1, h1);
  k_gemm<8><<<dim3(32, 8), 256, 0, stream>>>(h1, w2, part, 4096);
  k_finalize<8, true><<<512, 256, 0, stream>>>(part, b2, h2);
  k_gemm3<<<BATCH, 256, 0, stream>>>(h2, w3, b3, out);
}

// Round 2
// 263.123 us; speedup vs baseline: 1.5053x; 1.5053x over previous
//
#include <hip/hip_runtime.h>
#include <hip/hip_bf16.h>
#include <math.h>

#define BATCH 128
#define NPRI  8732
#define CCH   512
#define HH    19
#define NHID  4096
#define FGC   19

typedef unsigned short ushort_t;
typedef __attribute__((ext_vector_type(8))) short bf16x8;
typedef __attribute__((ext_vector_type(4))) float f32x4;

// RNE fp32 -> bf16 (finite values)
__device__ __forceinline__ ushort_t f2bf(float f) {
  unsigned u = __float_as_uint(f);
  u += 0x7fff + ((u >> 16) & 1);
  return (ushort_t)(u >> 16);
}

// ws byte layout
// [0, 16MB)          : part  (8 x 128 x 4096 fp32)   -- reused by both GEMMs
// [16MB, +1.25MB)    : part3 (128 x 128 x 19 fp32)
// then h2 fp32 2MB, feat bf16 128KB, h1 bf16 1MB, cand buffers

// ---------------------------------------------------------------------------
// K1a: per-(batch, quarter) partial argmax of car score (unchanged, correct)
// ---------------------------------------------------------------------------
__global__ void k_best_partial(const float* __restrict__ conf,
                               float* __restrict__ cs, int* __restrict__ ci,
                               int* __restrict__ cc) {
  int blk = blockIdx.x;
  int b = blk >> 2, chunk = blk & 3;
  int n0 = chunk * 2183;
  int t = threadIdx.x;
  const float* cb = conf + (size_t)b * NPRI * 2;
  float bestS = -INFINITY; int bestN = 0x7fffffff; int car_any = 0;
  for (int i = n0 + t; i < n0 + 2183; i += 256) {
    float c0 = cb[2 * i], c1 = cb[2 * i + 1];
    float m = fmaxf(c0, c1);
    float e0 = expf(c0 - m), e1 = expf(c1 - m);
    float s = e0 + e1;
    float p0 = e0 / s, p1 = e1 / s;
    bool car = p1 > p0;
    car_any |= (int)car;
    float sc = car ? p1 : -INFINITY;
    if (sc > bestS || (sc == bestS && i < bestN)) { bestS = sc; bestN = i; }
  }
  __shared__ float ls[256]; __shared__ int li[256]; __shared__ int lc[256];
  ls[t] = bestS; li[t] = bestN; lc[t] = car_any;
  __syncthreads();
  for (int off = 128; off > 0; off >>= 1) {
    if (t < off) {
      float s2 = ls[t + off]; int n2 = li[t + off];
      if (s2 > ls[t] || (s2 == ls[t] && n2 < li[t])) { ls[t] = s2; li[t] = n2; }
      lc[t] |= lc[t + off];
    }
    __syncthreads();
  }
  if (t == 0) { cs[blk] = ls[0]; ci[blk] = li[0]; cc[blk] = lc[0]; }
}

// ---------------------------------------------------------------------------
// K1b: combine + decode + outputs + crop coords (unchanged)
// ---------------------------------------------------------------------------
__global__ void k_best_final(const float* __restrict__ loc,
                             const float* __restrict__ priors,
                             const float* __restrict__ cs,
                             const int* __restrict__ ci,
                             const int* __restrict__ cc,
                             float* __restrict__ out_boxes,
                             float* __restrict__ out_valid,
                             int4* __restrict__ crop,
                             int* __restrict__ vflag) {
  int b = threadIdx.x;
  if (b >= BATCH) return;
  float bs = -INFINITY; int bn = 0; int hc = 0;
  #pragma unroll
  for (int p = 0; p < 4; p++) {
    float s = cs[b * 4 + p]; int n = ci[b * 4 + p];
    hc |= cc[b * 4 + p];
    if (s > bs) { bs = s; bn = n; }
  }
  const float* lp = loc + ((size_t)b * NPRI + bn) * 4;
  const float* pp = priors + (size_t)bn * 4;
  float l0 = lp[0], l1 = lp[1], l2 = lp[2], l3 = lp[3];
  float pcx = pp[0], pcy = pp[1], pw = pp[2], ph = pp[3];
  float cx = pcx + (l0 * 0.1f) * pw;
  float cy = pcy + (l1 * 0.1f) * ph;
  float w = pw * expf(l2 * 0.2f);
  float h = ph * expf(l3 * 0.2f);
  float x1 = cx - 0.5f * w;
  float y1 = cy - 0.5f * h;
  float x2 = x1 + w, y2 = y1 + h;
  bool geom = (x2 > x1) && (y2 > y1);
  bool valid = hc && geom;
  float r0, r1, r2, r3;
  if (hc) { r0 = x1; r1 = y1; r2 = x2; r3 = y2; }
  else    { r0 = r1 = r2 = r3 = 0.0f; }
  r0 = fminf(fmaxf(r0, 0.0f), 1.0f);
  r1 = fminf(fmaxf(r1, 0.0f), 1.0f);
  r2 = fminf(fmaxf(r2, 0.0f), 1.0f);
  r3 = fminf(fmaxf(r3, 0.0f), 1.0f);
  out_boxes[b * 4 + 0] = r0; out_boxes[b * 4 + 1] = r1;
  out_boxes[b * 4 + 2] = r2; out_boxes[b * 4 + 3] = r3;
  out_valid[b] = valid ? 1.0f : 0.0f;
  const float stepF = (float)(300.0 / 19.0);
  float q0 = fminf(fmaxf(r0 * 300.0f, 0.0f), 300.0f) / stepF;
  float q1 = fminf(fmaxf(r1 * 300.0f, 0.0f), 300.0f) / stepF;
  float q2 = fminf(fmaxf(r2 * 300.0f, 0.0f), 300.0f) / stepF;
  float q3 = fminf(fmaxf(r3 * 300.0f, 0.0f), 300.0f) / stepF;
  int ix1 = (int)floorf(fminf(fmaxf(q0, 0.0f), 18.0f));
  int iy1 = (int)floorf(fminf(fmaxf(q1, 0.0f), 18.0f));
  int ix2 = (int)floorf(fminf(fmaxf(q2, 0.0f), 18.0f));
  int iy2 = (int)floorf(fminf(fmaxf(q3, 0.0f), 18.0f));
  crop[b] = make_int4(ix1, iy1, ix2, iy2);
  vflag[b] = valid ? 1 : 0;
}

// ---------------------------------------------------------------------------
// K2: crop + global max pool -> bf16 feat
// ---------------------------------------------------------------------------
__global__ void k_extract(const float* __restrict__ fin,
                          const int4* __restrict__ crop,
                          const int* __restrict__ vflag,
                          ushort_t* __restrict__ feat) {
  int blk = blockIdx.x;
  int b = blk >> 7;
  int tile = blk & 127;
  int wave = threadIdx.x >> 6;
  int lane = threadIdx.x & 63;
  int c = tile * 4 + wave;
  if (!vflag[b]) {
    if (lane == 0) feat[b * CCH + c] = 0;
    return;
  }
  int4 cr = crop[b];
  int wcnt = cr.z - cr.x + 1;
  int cnt = wcnt * (cr.w - cr.y + 1);
  const float* p = fin + (size_t)(b * CCH + c) * (HH * HH);
  float m = -INFINITY;
  for (int i = lane; i < cnt; i += 64) {
    int yy = cr.y + i / wcnt;
    int xx = cr.x + i % wcnt;
    m = fmaxf(m, p[yy * HH + xx]);
  }
  #pragma unroll
  for (int off = 32; off > 0; off >>= 1) m = fmaxf(m, __shfl_xor(m, off));
  if (lane == 0) feat[b * CCH + c] = f2bf(m);
}

// ---------------------------------------------------------------------------
// K3: bf16 MFMA GEMM. A bf16 [128,K], W fp32 [K,4096] converted in-register.
// Block tile: 128m x 64n x (K/KSPL)k. 256 thr = 4 waves, wave tile 64m x 32n.
// LDS: As[128][40] bf16 (pad->2-way max), Bs[64][40] bf16 (k-major, transposed
// from W during staging). Grid (64, KSPL). Writes fp32 partials.
// ---------------------------------------------------------------------------
template <int KSPL>
__global__ __launch_bounds__(256) void k_mfma(const ushort_t* __restrict__ A,
                                              const float* __restrict__ W,
                                              float* __restrict__ part, int K) {
  const int N = 4096;
  const int BK = 32;
  int nb = blockIdx.x;             // 64 n-tiles of 64
  int ks = blockIdx.y;
  int Kper = K / KSPL;
  int k0b = ks * Kper;
  int t = threadIdx.x;
  int lane = t & 63, wave = t >> 6;
  int q = lane >> 4, r = lane & 15;

  __shared__ ushort_t As[128 * 40];   // 10240 B, row stride 40 (80 B)
  __shared__ ushort_t Bs[64 * 40];    // 5120 B

  int wm = (wave & 1) * 64;
  int wn = (wave >> 1) * 32;
  int n0 = nb * 64;

  f32x4 acc[4][2];
  #pragma unroll
  for (int i = 0; i < 4; i++)
    #pragma unroll
    for (int j = 0; j < 2; j++) {
      acc[i][j].x = 0.f; acc[i][j].y = 0.f; acc[i][j].z = 0.f; acc[i][j].w = 0.f;
    }

  // staging assignments
  int am = t >> 1, ah = t & 1;        // A: row, 16-element half
  int bp = t >> 4;                    // W: k-pair index (0..15)
  int bn = t & 15;                    // W: base n (strided by 16)

  for (int k0 = k0b; k0 < k0b + Kper; k0 += BK) {
    // --- global loads (issue before barrier) ---
    const uint4* asrc = (const uint4*)(A + (size_t)am * K + k0 + ah * 16);
    uint4 a0 = asrc[0];
    uint4 a1 = asrc[1];
    const float* wsrc = W + (size_t)(k0 + 2 * bp) * N + n0 + bn;
    float wr0[4], wr1[4];
    #pragma unroll
    for (int i = 0; i < 4; i++) {
      wr0[i] = wsrc[16 * i];          // k even
      wr1[i] = wsrc[N + 16 * i];      // k odd
    }
    __syncthreads();                  // previous iter's readers done
    // --- LDS stores ---
    *(uint4*)&As[am * 40 + ah * 16]     = a0;
    *(uint4*)&As[am * 40 + ah * 16 + 8] = a1;
    #pragma unroll
    for (int i = 0; i < 4; i++) {
      unsigned pk = (unsigned)f2bf(wr0[i]) | ((unsigned)f2bf(wr1[i]) << 16);
      *(unsigned*)&Bs[(bn + 16 * i) * 40 + 2 * bp] = pk;
    }
    __syncthreads();
    // --- fragments + MFMA ---
    bf16x8 af[4], bfr[2];
    #pragma unroll
    for (int i = 0; i < 4; i++)
      af[i] = *(const bf16x8*)&As[(wm + 16 * i + r) * 40 + q * 8];
    #pragma unroll
    for (int j = 0; j < 2; j++)
      bfr[j] = *(const bf16x8*)&Bs[(wn + 16 * j + r) * 40 + q * 8];
    #pragma unroll
    for (int i = 0; i < 4; i++)
      #pragma unroll
      for (int j = 0; j < 2; j++)
        acc[i][j] = __builtin_amdgcn_mfma_f32_16x16x32_bf16(af[i], bfr[j],
                                                            acc[i][j], 0, 0, 0);
  }

  // epilogue: D row = q*4 + reg (+ tile), col = r (+ tile)
  float* dst = part + (size_t)ks * (BATCH * N);
  #pragma unroll
  for (int i = 0; i < 4; i++) {
    #pragma unroll
    for (int j = 0; j < 2; j++) {
      int col = n0 + wn + 16 * j + r;
      #pragma unroll
      for (int reg = 0; reg < 4; reg++) {
        int row = wm + 16 * i + q * 4 + reg;
        dst[(size_t)row * N + col] = acc[i][j][reg];
      }
    }
  }
}

// ---------------------------------------------------------------------------
// K4: sum KSPL partials + bias + relu; fp32 or bf16 output
// ---------------------------------------------------------------------------
template <int KSPL, bool BF16OUT>
__global__ void k_finalize(const float* __restrict__ part,
                           const float* __restrict__ bias,
                           float* __restrict__ outf,
                           ushort_t* __restrict__ outb) {
  int idx = (blockIdx.x * 256 + threadIdx.x) * 4;
  float4 s = *(const float4*)(part + idx);
  #pragma unroll
  for (int p = 1; p < KSPL; p++) {
    float4 v = *(const float4*)(part + (size_t)p * (BATCH * NHID) + idx);
    s.x += v.x; s.y += v.y; s.z += v.z; s.w += v.w;
  }
  float4 bv = *(const float4*)(bias + (idx & (NHID - 1)));
  s.x = fmaxf(s.x + bv.x, 0.0f); s.y = fmaxf(s.y + bv.y, 0.0f);
  s.z = fmaxf(s.z + bv.z, 0.0f); s.w = fmaxf(s.w + bv.w, 0.0f);
  if (BF16OUT) {
    ushort4 o;
    o.x = f2bf(s.x); o.y = f2bf(s.y); o.z = f2bf(s.z); o.w = f2bf(s.w);
    *(ushort4*)(outb + idx) = o;
  } else {
    *(float4*)(outf + idx) = s;
  }
}

// ---------------------------------------------------------------------------
// K5: final projection partials. 128 blocks x 32-k chunks; thread = one m row.
// ---------------------------------------------------------------------------
__global__ void k_gemm3p(const float* __restrict__ h2,
                         const float* __restrict__ w3,
                         float* __restrict__ part3) {
  int kc = blockIdx.x;             // 128 chunks of 32 k
  int t = threadIdx.x;             // 128 threads, m = t
  __shared__ float wl[32 * FGC];
  for (int i = t; i < 32 * FGC; i += 128) wl[i] = w3[kc * 32 * FGC + i];
  __syncthreads();
  const float* hp = h2 + (size_t)t * NHID + kc * 32;
  float acc[FGC];
  #pragma unroll
  for (int j = 0; j < FGC; j++) acc[j] = 0.0f;
  for (int k = 0; k < 32; k++) {
    float hv = hp[k];
    const float* wp = &wl[k * FGC];
    #pragma unroll
    for (int j = 0; j < FGC; j++) acc[j] += hv * wp[j];
  }
  float* dst = part3 + (size_t)kc * (BATCH * FGC) + t * FGC;
  #pragma unroll
  for (int j = 0; j < FGC; j++) dst[j] = acc[j];
}

__global__ void k_fin3(const float* __restrict__ part3,
                       const float* __restrict__ b3,
                       float* __restrict__ out) {
  int j = blockIdx.x * 256 + threadIdx.x;
  if (j >= BATCH * FGC) return;
  float s = 0.0f;
  for (int p = 0; p < 128; p++) s += part3[(size_t)p * (BATCH * FGC) + j];
  out[j] = s + b3[j % FGC];
}

// ---------------------------------------------------------------------------
extern "C" void kernel_launch(void* const* d_in, const int* in_sizes, int n_in,
                              void* d_out, int out_size, void* d_ws, size_t ws_size,
                              hipStream_t stream) {
  const float* loc      = (const float*)d_in[0];
  const float* conf     = (const float*)d_in[1];
  const float* priors   = (const float*)d_in[2];
  const float* features = (const float*)d_in[3];
  const float* w1 = (const float*)d_in[4];
  const float* b1 = (const float*)d_in[5];
  const float* w2 = (const float*)d_in[6];
  const float* b2 = (const float*)d_in[7];
  const float* w3 = (const float*)d_in[8];
  const float* b3 = (const float*)d_in[9];
  float* out = (float*)d_out;      // [128*19 fg][128*4 boxes][128 valid]

  char* ws = (char*)d_ws;
  float*    part  = (float*)ws;                               // 16 MB
  float*    part3 = (float*)(ws + (size_t)16 * 1024 * 1024);  // 1.25 MB
  float*    h2    = (float*)(ws + (size_t)18 * 1024 * 1024);  // 2 MB
  ushort_t* featb = (ushort_t*)(ws + (size_t)20 * 1024 * 1024);   // 128 KB
  ushort_t* h1b   = (ushort_t*)(ws + (size_t)20 * 1024 * 1024 + 256 * 1024); // 1MB
  float*    cs    = (float*)(ws + (size_t)21 * 1024 * 1024 + 512 * 1024);
  int*      ci    = (int*)(cs + 512);
  int*      cc    = ci + 512;
  int4*     crop  = (int4*)(cc + 512);
  int*      vfl   = (int*)(crop + BATCH);

  k_best_partial<<<512, 256, 0, stream>>>(conf, cs, ci, cc);
  k_best_final<<<1, 128, 0, stream>>>(loc, priors, cs, ci, cc,
                                      out + BATCH * FGC,
                                      out + BATCH * FGC + BATCH * 4, crop, vfl);
  k_extract<<<BATCH * (CCH / 4), 256, 0, stream>>>(features, crop, vfl, featb);
  k_mfma<4><<<dim3(64, 4), 256, 0, stream>>>(featb, w1, part, 512);
  k_finalize<4, true><<<512, 256, 0, stream>>>(part, b1, nullptr, h1b);
  k_mfma<8><<<dim3(64, 8), 256, 0, stream>>>(h1b, w2, part, 4096);
  k_finalize<8, false><<<512, 256, 0, stream>>>(part, b2, h2, nullptr);
  k_gemm3p<<<128, 128, 0, stream>>>(h2, w3, part3);
  k_fin3<<<10, 256, 0, stream>>>(part3, b3, out);
}